// Round 1
// baseline (214.177 us; speedup 1.0000x reference)
//
#include <hip/hip_runtime.h>

// YOLO loss: input [B,30,7,7] f32, target [B,7,7,30] f32 -> scalar f32.
// Memory-bound: 192.7 MB read -> ~30.6 us floor at 6.3 TB/s.

#define NCH   30
#define CELLS 49
#define TPB   256
#define IMGSZ 448.0f
#define CELLSZ 64.0f

__device__ __forceinline__ float iou_f(float ax1, float ay1, float ax2, float ay2,
                                       float bx1, float by1, float bx2, float by2) {
    float l  = fmaxf(ax1, bx1);
    float r  = fminf(ax2, bx2);
    float t  = fmaxf(ay1, by1);
    float bo = fminf(ay2, by2);
    bool  m  = (l < r) && (t < bo);
    float inter = (r - l) * (bo - t);
    float uni   = (ax2 - ax1) * (ay2 - ay1) + (bx2 - bx1) * (by2 - by1);
    float denom = uni - inter;
    return m ? (inter / denom) : 0.0f;
}

__device__ __forceinline__ void decode_box(float p0, float p1, float p2, float p3,
                                           float gx, float gy,
                                           float& x1, float& y1, float& x2, float& y2) {
    float cx = p0 * CELLSZ + gx;
    float cy = p1 * CELLSZ + gy;
    float w  = p2 * IMGSZ;
    float h  = p3 * IMGSZ;
    x1 = fminf(fmaxf(cx - w * 0.5f, 0.0f), IMGSZ);
    y1 = fminf(fmaxf(cy - h * 0.5f, 0.0f), IMGSZ);
    x2 = fminf(fmaxf(cx + w * 0.5f, 0.0f), IMGSZ);
    y2 = fminf(fmaxf(cy + h * 0.5f, 0.0f), IMGSZ);
}

__global__ __launch_bounds__(TPB) void yolo_loss_kernel(
        const float* __restrict__ input,   // [B,30,7,7]
        const float* __restrict__ target,  // [B,7,7,30] == [N,30]
        float* __restrict__ out,
        int ncells) {
    // Stage this block's target tile into LDS with coalesced float2 loads.
    // Padded stride 31 (odd) -> conflict-free strided reads later.
    __shared__ float st[TPB * 31];
    __shared__ float red[TPB / 64];

    const int tid   = threadIdx.x;
    const int cell0 = blockIdx.x * TPB;

    // 256 cells * 30 ch = 7680 floats = 3840 float2 = 15 float2/thread.
    const float2* __restrict__ t2 = reinterpret_cast<const float2*>(target) + (long long)cell0 * 15;
    const int max_f2 = (ncells - cell0) * 15;  // float2s available in this tile
    #pragma unroll
    for (int k = 0; k < 15; ++k) {
        int i = tid + k * TPB;       // float2 index within tile
        if (i < max_f2) {
            float2 v = t2[i];
            int fi = 2 * i;          // float index; even, and 30 even -> pair stays in one cell
            int c  = fi / 30;
            int ch = fi - c * 30;
            st[c * 31 + ch]     = v.x;
            st[c * 31 + ch + 1] = v.y;
        }
    }
    __syncthreads();

    const int n = cell0 + tid;
    float loss = 0.0f;
    if (n < ncells) {
        const int b    = n / CELLS;
        const int cell = n - b * CELLS;
        const int row  = cell / 7;
        const int col  = cell - row * 7;
        const float gx = (float)col * CELLSZ;
        const float gy = (float)row * CELLSZ;

        // input[b][c][row][col] = input[b*1470 + c*49 + cell]
        const float* __restrict__ ip = input + b * (NCH * CELLS) + cell;
        float x[NCH];
        #pragma unroll
        for (int c = 0; c < NCH; ++c) x[c] = ip[c * CELLS];

        const float* __restrict__ tl = &st[tid * 31];

        // Decode predicted boxes
        float p0x1, p0y1, p0x2, p0y2, p1x1, p1y1, p1x2, p1y2;
        decode_box(x[0], x[1], x[2], x[3], gx, gy, p0x1, p0y1, p0x2, p0y2);
        decode_box(x[5], x[6], x[7], x[8], gx, gy, p1x1, p1y1, p1x2, p1y2);
        // Decode target boxes
        float t0x1, t0y1, t0x2, t0y2, t1x1, t1y1, t1x2, t1y2;
        decode_box(tl[0], tl[1], tl[2], tl[3], gx, gy, t0x1, t0y1, t0x2, t0y2);
        decode_box(tl[5], tl[6], tl[7], tl[8], gx, gy, t1x1, t1y1, t1x2, t1y2);

        float iou1 = iou_f(p0x1, p0y1, p0x2, p0y2, t0x1, t0y1, t0x2, t0y2);
        float iou2 = iou_f(p1x1, p1y1, p1x2, p1y2, t1x1, t1y1, t1x2, t1y2);

        bool  mask = iou1 < iou2;
        float iou  = mask ? iou2 : iou1;
        float s0 = mask ? x[5] : x[0];
        float s1 = mask ? x[6] : x[1];
        float s2 = mask ? x[7] : x[2];
        float s3 = mask ? x[8] : x[3];
        float s4 = mask ? x[9] : x[4];

        float w = (tl[4] == 1.0f) ? 1.0f : 0.0f;

        float d0 = s0 - tl[0];
        float d1 = s1 - tl[1];
        float coord = d0 * d0 + d1 * d1;

        float ds2 = sqrtf(s2) - sqrtf(tl[2]);
        float ds3 = sqrtf(s3) - sqrtf(tl[3]);
        float size = ds2 * ds2 + ds3 * ds3;

        float dc = s4 - iou;
        float conf = dc * dc;
        float noobj = s4 * s4;

        float cls = 0.0f;
        #pragma unroll
        for (int c = 10; c < NCH; ++c) {
            float d = x[c] - tl[c];
            cls += d * d;
        }

        loss = w * (5.0f * (coord + size) + conf + cls) + 0.5f * (1.0f - w) * noobj;
    }

    // Wave reduce (64 lanes), then block reduce, one atomic per block.
    #pragma unroll
    for (int off = 32; off > 0; off >>= 1)
        loss += __shfl_down(loss, off, 64);

    const int wid  = tid >> 6;
    const int lane = tid & 63;
    if (lane == 0) red[wid] = loss;
    __syncthreads();
    if (tid == 0) {
        float s = 0.0f;
        #pragma unroll
        for (int i = 0; i < TPB / 64; ++i) s += red[i];
        atomicAdd(out, s);
    }
}

extern "C" void kernel_launch(void* const* d_in, const int* in_sizes, int n_in,
                              void* d_out, int out_size, void* d_ws, size_t ws_size,
                              hipStream_t stream) {
    const float* input  = (const float*)d_in[0];   // [B,30,7,7]
    const float* target = (const float*)d_in[1];   // [B,7,7,30]
    float* out = (float*)d_out;

    const int ncells = in_sizes[0] / NCH;          // B*49 = 802816
    const int blocks = (ncells + TPB - 1) / TPB;   // 3136

    // d_out is poisoned 0xAA before every timed launch -> zero it (capture-safe).
    hipMemsetAsync(d_out, 0, sizeof(float), stream);
    yolo_loss_kernel<<<blocks, TPB, 0, stream>>>(input, target, out, ncells);
}

// Round 2
// 207.326 us; speedup vs baseline: 1.0330x; 1.0330x over previous
//
#include <hip/hip_runtime.h>

// YOLO loss: input [B,30,7,7] f32, target [B,7,7,30] f32 -> scalar f32.
// Latency-bound fix (round 2): no LDS staging, no barrier. Target is loaded
// per-thread as 15 float2 (cell base = n*120 B, always 8B-aligned); each 64B
// line is touched ~8x by neighboring offsets and served by L1 (7.5 KB/wave
// working set << 32 KB L1). Occupancy becomes VGPR-bound instead of LDS-bound.

#define NCH   30
#define CELLS 49
#define TPB   256
#define IMGSZ 448.0f
#define CELLSZ 64.0f

__device__ __forceinline__ float iou_f(float ax1, float ay1, float ax2, float ay2,
                                       float bx1, float by1, float bx2, float by2) {
    float l  = fmaxf(ax1, bx1);
    float r  = fminf(ax2, bx2);
    float t  = fmaxf(ay1, by1);
    float bo = fminf(ay2, by2);
    bool  m  = (l < r) && (t < bo);
    float inter = (r - l) * (bo - t);
    float uni   = (ax2 - ax1) * (ay2 - ay1) + (bx2 - bx1) * (by2 - by1);
    float denom = uni - inter;
    return m ? (inter / denom) : 0.0f;
}

__device__ __forceinline__ void decode_box(float p0, float p1, float p2, float p3,
                                           float gx, float gy,
                                           float& x1, float& y1, float& x2, float& y2) {
    float cx = p0 * CELLSZ + gx;
    float cy = p1 * CELLSZ + gy;
    float w  = p2 * IMGSZ;
    float h  = p3 * IMGSZ;
    x1 = fminf(fmaxf(cx - w * 0.5f, 0.0f), IMGSZ);
    y1 = fminf(fmaxf(cy - h * 0.5f, 0.0f), IMGSZ);
    x2 = fminf(fmaxf(cx + w * 0.5f, 0.0f), IMGSZ);
    y2 = fminf(fmaxf(cy + h * 0.5f, 0.0f), IMGSZ);
}

__global__ __launch_bounds__(TPB) void yolo_loss_kernel(
        const float* __restrict__ input,   // [B,30,7,7]
        const float* __restrict__ target,  // [B,7,7,30] == [N,30]
        float* __restrict__ out,
        int ncells) {
    __shared__ float red[TPB / 64];

    const int tid = threadIdx.x;
    const int n   = blockIdx.x * TPB + tid;

    float loss = 0.0f;
    if (n < ncells) {
        // ---- issue all loads up front (45 independent VMEM ops / thread) ----
        // target cell: 30 floats at byte offset n*120 (8B-aligned) -> 15 float2
        const float2* __restrict__ tp = reinterpret_cast<const float2*>(target) + (long long)n * 15;
        float2 tv[15];
        #pragma unroll
        for (int k = 0; k < 15; ++k) tv[k] = tp[k];

        const int b    = n / CELLS;
        const int cell = n - b * CELLS;
        // input[b][c][cell] = input[b*1470 + c*49 + cell]
        const float* __restrict__ ip = input + b * (NCH * CELLS) + cell;
        float x[NCH];
        #pragma unroll
        for (int c = 0; c < NCH; ++c) x[c] = ip[c * CELLS];

        float tl[NCH];
        #pragma unroll
        for (int k = 0; k < 15; ++k) { tl[2 * k] = tv[k].x; tl[2 * k + 1] = tv[k].y; }

        const int row  = cell / 7;
        const int col  = cell - row * 7;
        const float gx = (float)col * CELLSZ;
        const float gy = (float)row * CELLSZ;

        // Decode predicted boxes
        float p0x1, p0y1, p0x2, p0y2, p1x1, p1y1, p1x2, p1y2;
        decode_box(x[0], x[1], x[2], x[3], gx, gy, p0x1, p0y1, p0x2, p0y2);
        decode_box(x[5], x[6], x[7], x[8], gx, gy, p1x1, p1y1, p1x2, p1y2);
        // Decode target boxes
        float t0x1, t0y1, t0x2, t0y2, t1x1, t1y1, t1x2, t1y2;
        decode_box(tl[0], tl[1], tl[2], tl[3], gx, gy, t0x1, t0y1, t0x2, t0y2);
        decode_box(tl[5], tl[6], tl[7], tl[8], gx, gy, t1x1, t1y1, t1x2, t1y2);

        float iou1 = iou_f(p0x1, p0y1, p0x2, p0y2, t0x1, t0y1, t0x2, t0y2);
        float iou2 = iou_f(p1x1, p1y1, p1x2, p1y2, t1x1, t1y1, t1x2, t1y2);

        bool  mask = iou1 < iou2;
        float iou  = mask ? iou2 : iou1;
        float s0 = mask ? x[5] : x[0];
        float s1 = mask ? x[6] : x[1];
        float s2 = mask ? x[7] : x[2];
        float s3 = mask ? x[8] : x[3];
        float s4 = mask ? x[9] : x[4];

        float w = (tl[4] == 1.0f) ? 1.0f : 0.0f;

        float d0 = s0 - tl[0];
        float d1 = s1 - tl[1];
        float coord = d0 * d0 + d1 * d1;

        float ds2 = sqrtf(s2) - sqrtf(tl[2]);
        float ds3 = sqrtf(s3) - sqrtf(tl[3]);
        float size = ds2 * ds2 + ds3 * ds3;

        float dc = s4 - iou;
        float conf = dc * dc;
        float noobj = s4 * s4;

        float cls = 0.0f;
        #pragma unroll
        for (int c = 10; c < NCH; ++c) {
            float d = x[c] - tl[c];
            cls += d * d;
        }

        loss = w * (5.0f * (coord + size) + conf + cls) + 0.5f * (1.0f - w) * noobj;
    }

    // Wave reduce (64 lanes), then block reduce, one atomic per block.
    #pragma unroll
    for (int off = 32; off > 0; off >>= 1)
        loss += __shfl_down(loss, off, 64);

    const int wid  = tid >> 6;
    const int lane = tid & 63;
    if (lane == 0) red[wid] = loss;
    __syncthreads();
    if (tid == 0) {
        float s = 0.0f;
        #pragma unroll
        for (int i = 0; i < TPB / 64; ++i) s += red[i];
        atomicAdd(out, s);
    }
}

extern "C" void kernel_launch(void* const* d_in, const int* in_sizes, int n_in,
                              void* d_out, int out_size, void* d_ws, size_t ws_size,
                              hipStream_t stream) {
    const float* input  = (const float*)d_in[0];   // [B,30,7,7]
    const float* target = (const float*)d_in[1];   // [B,7,7,30]
    float* out = (float*)d_out;

    const int ncells = in_sizes[0] / NCH;          // B*49 = 802816
    const int blocks = (ncells + TPB - 1) / TPB;   // 3136

    // d_out is poisoned 0xAA before every timed launch -> zero it (capture-safe).
    hipMemsetAsync(d_out, 0, sizeof(float), stream);
    yolo_loss_kernel<<<blocks, TPB, 0, stream>>>(input, target, out, ncells);
}

// Round 3
// 204.147 us; speedup vs baseline: 1.0491x; 1.0156x over previous
//
#include <hip/hip_runtime.h>

// YOLO loss: input [B,30,7,7] f32, target [B,7,7,30] f32 -> scalar f32.
//
// Round 3: attack the real limiter found in round 2's counters — MLP.
// VGPR_Count=40 vs ~60 floats of live data meant the compiler serialized the
// 45 loads (Little's law from measured 1.5 TB/s: ~2 outstanding loads/wave).
// __launch_bounds__(256, 4) sets the budget to 128 VGPR/wave at 16 waves/CU
// (the occupancy we already measured), letting all 45 loads stay in flight
// before the first consume.

#define NCH   30
#define CELLS 49
#define TPB   256
#define IMGSZ 448.0f
#define CELLSZ 64.0f

__device__ __forceinline__ float iou_f(float ax1, float ay1, float ax2, float ay2,
                                       float bx1, float by1, float bx2, float by2) {
    float l  = fmaxf(ax1, bx1);
    float r  = fminf(ax2, bx2);
    float t  = fmaxf(ay1, by1);
    float bo = fminf(ay2, by2);
    bool  m  = (l < r) && (t < bo);
    float inter = (r - l) * (bo - t);
    float uni   = (ax2 - ax1) * (ay2 - ay1) + (bx2 - bx1) * (by2 - by1);
    float denom = uni - inter;
    return m ? (inter / denom) : 0.0f;
}

__device__ __forceinline__ void decode_box(float p0, float p1, float p2, float p3,
                                           float gx, float gy,
                                           float& x1, float& y1, float& x2, float& y2) {
    float cx = p0 * CELLSZ + gx;
    float cy = p1 * CELLSZ + gy;
    float w  = p2 * IMGSZ;
    float h  = p3 * IMGSZ;
    x1 = fminf(fmaxf(cx - w * 0.5f, 0.0f), IMGSZ);
    y1 = fminf(fmaxf(cy - h * 0.5f, 0.0f), IMGSZ);
    x2 = fminf(fmaxf(cx + w * 0.5f, 0.0f), IMGSZ);
    y2 = fminf(fmaxf(cy + h * 0.5f, 0.0f), IMGSZ);
}

// 4 waves/EU target -> <=128 VGPR/wave, 16 waves/CU (matches measured occupancy)
__global__ __launch_bounds__(TPB, 4) void yolo_loss_kernel(
        const float* __restrict__ input,   // [B,30,7,7]
        const float* __restrict__ target,  // [B,7,7,30] == [N,30]
        float* __restrict__ out,
        int ncells) {
    __shared__ float red[TPB / 64];

    const int tid = threadIdx.x;
    const int n   = blockIdx.x * TPB + tid;

    float loss = 0.0f;
    if (n < ncells) {
        const int b    = n / CELLS;
        const int cell = n - b * CELLS;

        // ---- issue ALL 45 loads before any consumption ----
        const float2* __restrict__ tp =
            reinterpret_cast<const float2*>(target) + (long long)n * 15;
        const float* __restrict__ ip = input + b * (NCH * CELLS) + cell;

        float2 tv[15];
        float  x[NCH];
        #pragma unroll
        for (int k = 0; k < 15; ++k) tv[k] = tp[k];
        #pragma unroll
        for (int c = 0; c < NCH; ++c) x[c] = ip[c * CELLS];

        float tl[NCH];
        #pragma unroll
        for (int k = 0; k < 15; ++k) { tl[2 * k] = tv[k].x; tl[2 * k + 1] = tv[k].y; }

        const int row  = cell / 7;
        const int col  = cell - row * 7;
        const float gx = (float)col * CELLSZ;
        const float gy = (float)row * CELLSZ;

        float p0x1, p0y1, p0x2, p0y2, p1x1, p1y1, p1x2, p1y2;
        decode_box(x[0], x[1], x[2], x[3], gx, gy, p0x1, p0y1, p0x2, p0y2);
        decode_box(x[5], x[6], x[7], x[8], gx, gy, p1x1, p1y1, p1x2, p1y2);
        float t0x1, t0y1, t0x2, t0y2, t1x1, t1y1, t1x2, t1y2;
        decode_box(tl[0], tl[1], tl[2], tl[3], gx, gy, t0x1, t0y1, t0x2, t0y2);
        decode_box(tl[5], tl[6], tl[7], tl[8], gx, gy, t1x1, t1y1, t1x2, t1y2);

        float iou1 = iou_f(p0x1, p0y1, p0x2, p0y2, t0x1, t0y1, t0x2, t0y2);
        float iou2 = iou_f(p1x1, p1y1, p1x2, p1y2, t1x1, t1y1, t1x2, t1y2);

        bool  mask = iou1 < iou2;
        float iou  = mask ? iou2 : iou1;
        float s0 = mask ? x[5] : x[0];
        float s1 = mask ? x[6] : x[1];
        float s2 = mask ? x[7] : x[2];
        float s3 = mask ? x[8] : x[3];
        float s4 = mask ? x[9] : x[4];

        float w = (tl[4] == 1.0f) ? 1.0f : 0.0f;

        float d0 = s0 - tl[0];
        float d1 = s1 - tl[1];
        float coord = d0 * d0 + d1 * d1;

        float ds2 = sqrtf(s2) - sqrtf(tl[2]);
        float ds3 = sqrtf(s3) - sqrtf(tl[3]);
        float size = ds2 * ds2 + ds3 * ds3;

        float dc = s4 - iou;
        float conf = dc * dc;
        float noobj = s4 * s4;

        float cls = 0.0f;
        #pragma unroll
        for (int c = 10; c < NCH; ++c) {
            float d = x[c] - tl[c];
            cls += d * d;
        }

        loss = w * (5.0f * (coord + size) + conf + cls) + 0.5f * (1.0f - w) * noobj;
    }

    // Wave reduce (64 lanes), then block reduce, one atomic per block.
    #pragma unroll
    for (int off = 32; off > 0; off >>= 1)
        loss += __shfl_down(loss, off, 64);

    const int wid  = tid >> 6;
    const int lane = tid & 63;
    if (lane == 0) red[wid] = loss;
    __syncthreads();
    if (tid == 0) {
        float s = 0.0f;
        #pragma unroll
        for (int i = 0; i < TPB / 64; ++i) s += red[i];
        atomicAdd(out, s);
    }
}

extern "C" void kernel_launch(void* const* d_in, const int* in_sizes, int n_in,
                              void* d_out, int out_size, void* d_ws, size_t ws_size,
                              hipStream_t stream) {
    const float* input  = (const float*)d_in[0];   // [B,30,7,7]
    const float* target = (const float*)d_in[1];   // [B,7,7,30]
    float* out = (float*)d_out;

    const int ncells = in_sizes[0] / NCH;          // B*49 = 802816
    const int blocks = (ncells + TPB - 1) / TPB;   // 3136

    // d_out is poisoned 0xAA before every timed launch -> zero it (capture-safe).
    hipMemsetAsync(d_out, 0, sizeof(float), stream);
    yolo_loss_kernel<<<blocks, TPB, 0, stream>>>(input, target, out, ncells);
}